// Round 13
// baseline (367.077 us; speedup 1.0000x reference)
//
#include <hip/hip_runtime.h>
#include <math.h>

#define B_  2
#define C_  128
#define N_  6000
#define M_  1500
#define H_  4
#define DH_ 32

typedef __attribute__((ext_vector_type(8))) short bf16x8;   // 8 bf16 = 4 VGPRs
typedef __attribute__((ext_vector_type(4))) float f32x4;
typedef unsigned short u16;

static __device__ __forceinline__ u16 f2bf(float x) {
    unsigned u = __float_as_uint(x);
    return (u16)((u + 0x7fffu + ((u >> 16) & 1u)) >> 16);   // RNE
}
#define MFMA(a,b,c) __builtin_amdgcn_mfma_f32_16x16x32_bf16((a),(b),(c),0,0,0)
// exp2-domain softmax: Q pre-scaled by (1/sqrt(32))*log2(e) in qkv_kernel
#define INVS2 (0.17677669529663687f * 1.4426950408889634f)

// ---------------------------------------------------------------- prep: weights->bf16, zero stats + pacc/pl
__global__ __launch_bounds__(256) void prep_kernel(
    const float* __restrict__ Wq, const float* __restrict__ Wk, const float* __restrict__ Wv,
    const float* __restrict__ Wm, const float* __restrict__ Wc1, const float* __restrict__ Wc2,
    const float* __restrict__ iW1,
    u16* __restrict__ wq, u16* __restrict__ wk, u16* __restrict__ wv, u16* __restrict__ wm,
    u16* __restrict__ wc1, u16* __restrict__ wc2, u16* __restrict__ w1,
    float* __restrict__ zstats, float* __restrict__ pz, long pzN)
{
    long i = (long)blockIdx.x * 256 + threadIdx.x;
    if (i < 512)    zstats[i] = 0.f;
    if (i < 49152)  { wq[i] = f2bf(Wq[i]); wk[i] = f2bf(Wk[i]);
                      wv[i] = f2bf(Wv[i]); wm[i] = f2bf(Wm[i]); }
    if (i < 196608) wc1[i] = f2bf(Wc1[i]);
    if (i < 98304)  wc2[i] = f2bf(Wc2[i]);
    if (i < 8192)   w1[i]  = f2bf(iW1[i]);
    for (long j = i; j < pzN; j += 768L * 256) pz[j] = 0.f;   // pacc + pl (contiguous)
}

// ---------------------------------------------------------------- fused q/k/v conv (MFMA, CIN=128)
// Layouts: Q16 [bh][Nq][32] (pre-scaled by INVS2); K16 [bh][Nkpad][32] (pads zeroed);
//          V16 [bh][48][Nkpad]: rows 0-31 = V dh (pads zeroed), rows 32-47 zero (PV B-frag overrun pad).
__global__ __launch_bounds__(256) void qkv_kernel(
    const float* __restrict__ x1, const float* __restrict__ x2, int Pq, int Pk, int Pkpad,
    const u16* __restrict__ wq, const u16* __restrict__ wk, const u16* __restrict__ wv,
    const float* __restrict__ bq, const float* __restrict__ bk, const float* __restrict__ bv,
    u16* __restrict__ Q16, u16* __restrict__ K16, u16* __restrict__ V16)
{
    __shared__ u16 Xt[64][40];      // [pos][cin-chunk], row 80B
    const int tid = threadIdx.x;
    const int wid = tid >> 6, lane = tid & 63;
    const int l15 = lane & 15, quad = lane >> 4;
    const int job = blockIdx.y >> 1, ot = blockIdx.y & 1;
    const int b = blockIdx.z;
    const int p0 = blockIdx.x * 64;
    const float* X; const u16* W; const float* bias; int P;
    if (job == 0)      { X = x1; W = wq; bias = bq; P = Pq; }
    else if (job == 1) { X = x2; W = wk; bias = bk; P = Pk; }
    else               { X = x2; W = wv; bias = bv; P = Pk; }
    const int Plim = (job == 0) ? Pq : Pkpad;
    if (p0 < Plim) {
        const long xoff = (long)b * C_ * P;
        const int sp = tid & 63, cg = tid >> 6;
        f32x4 acc[4] = {};
        if (p0 < P) {
            for (int k0 = 0; k0 < 128; k0 += 32) {
                bf16x8 st;
                const int pp = (p0 + sp < P) ? p0 + sp : P - 1;
                #pragma unroll
                for (int j = 0; j < 8; ++j)
                    st[j] = (short)f2bf(X[xoff + (long)(k0 + cg * 8 + j) * P + pp]);
                __syncthreads();
                *(bf16x8*)&Xt[sp][cg * 8] = st;
                __syncthreads();
                const bf16x8 af = *(const bf16x8*)(W + (long)(ot * 64 + wid * 16 + l15) * 128 + k0 + quad * 8);
                #pragma unroll
                for (int pg = 0; pg < 4; ++pg) {
                    const bf16x8 bfr = *(const bf16x8*)&Xt[pg * 16 + l15][quad * 8];
                    acc[pg] = MFMA(af, bfr, acc[pg]);
                }
            }
        }
        #pragma unroll
        for (int pg = 0; pg < 4; ++pg)
            #pragma unroll
            for (int r = 0; r < 4; ++r) {
                const int o = ot * 64 + wid * 16 + quad * 4 + r;
                const int p = p0 + pg * 16 + l15;
                if (p >= Plim) continue;
                if (job == 0) {
                    if (p < Pq)
                        Q16[((long)(b * 4 + (o >> 5)) * Pq + p) * 32 + (o & 31)] =
                            f2bf((acc[pg][r] + bias[o]) * INVS2);
                } else {
                    const u16 v = (p < P) ? f2bf(acc[pg][r] + bias[o]) : (u16)0;
                    if (job == 1)
                        K16[((long)(b * 4 + (o >> 5)) * Pkpad + p) * 32 + (o & 31)] = v;
                    else
                        V16[((long)(b * 4 + (o >> 5)) * 48 + (o & 31)) * Pkpad + p] = v;
                }
            }
        if (job == 2) {     // rows 32..47 zero (B-frag reads may overrun into them)
            for (int e = tid; e < 2048; e += 256) {
                const int which = e >> 10;
                const int row = 32 + ((e >> 6) & 15);
                const int col = p0 + (e & 63);
                if (col < Pkpad)
                    V16[((long)(b * 4 + ot * 2 + which) * 48 + row) * Pkpad + col] = (u16)0;
            }
        }
    }
}

// ---------------------------------------------------------------- flash attention (MFMA, S^T, full tiles)
// R13: partials accumulated via global_atomic_add_f32 into KS-independent pacc[bh][q][32] / pl[bh][q].
// XCD-pinned grid (id%8==bh) keeps atomics L2-local. lp back in VALU (lp-MFMA was a measured loss).
template<bool MASKED>
__global__ __launch_bounds__(256) void attn_partial(
    const u16* __restrict__ Q16, const u16* __restrict__ K16, const u16* __restrict__ V16,
    const float* __restrict__ lgin,
    float* __restrict__ pl, float* __restrict__ pacc,
    int Nq, int Nk, int Nkpad, int KS, int chunkLen)
{
    __shared__ u16 Ps[4][32][72];   // per-wave P round-trip
    const int tid  = threadIdx.x;
    const int wave = tid >> 6, lane = tid & 63;
    const int l15  = lane & 15, quad = lane >> 4;
    const int bid  = blockIdx.x;
    const int bh   = bid & 7, rest = bid >> 3;
    const int split = rest % KS, qblk = rest / KS;
    const int b = bh >> 2;
    const int q0w = qblk * 128 + wave * 32;

    const u16* Qb = Q16 + (long)bh * Nq * 32;
    const u16* Kb = K16 + (long)bh * Nkpad * 32;
    const u16* Vb = V16 + (long)(bh * 48) * Nkpad;

    const int qq0 = min(q0w + l15, Nq - 1);
    const int qq1 = min(q0w + 16 + l15, Nq - 1);
    const bf16x8 qa0 = *(const bf16x8*)(Qb + (long)qq0 * 32 + quad * 8);
    const bf16x8 qa1 = *(const bf16x8*)(Qb + (long)qq1 * 32 + quad * 8);

    f32x4 o00={0,0,0,0}, o01={0,0,0,0}, o10={0,0,0,0}, o11={0,0,0,0};
    float lp0 = 0.f, lp1 = 0.f;
    const f32x4 z4 = {0,0,0,0};

    const int kbeg = split * chunkLen;
    const int kend = kbeg + chunkLen;        // full tiles (pads zeroed)

    for (int m0 = kbeg; m0 < kend; m0 += 64) {
        f32x4 sa0[4], sa1[4];
        #pragma unroll
        for (int kg = 0; kg < 4; ++kg) {
            const bf16x8 ka = *(const bf16x8*)(Kb + (long)(m0 + kg * 16 + l15) * 32 + quad * 8);
            sa0[kg] = MFMA(ka, qa0, z4);
            sa1[kg] = MFMA(ka, qa1, z4);
        }
        #pragma unroll
        for (int kg = 0; kg < 4; ++kg) {
            float p0[4], p1[4];
            if (MASKED) {
                const int kbase = m0 + kg * 16 + quad * 4;
                const float4 mv = *(const float4*)&lgin[(long)b * Nk + min(kbase, Nk - 4)];
                const float* mr = (const float*)&mv;
                #pragma unroll
                for (int r = 0; r < 4; ++r) {
                    const bool good = (kbase + r < Nk) && (mr[r] > 0.f);
                    p0[r] = good ? exp2f(sa0[kg][r]) : 0.f;
                    p1[r] = good ? exp2f(sa1[kg][r]) : 0.f;
                }
            } else {
                #pragma unroll
                for (int r = 0; r < 4; ++r) { p0[r] = exp2f(sa0[kg][r]); p1[r] = exp2f(sa1[kg][r]); }
            }
            lp0 += (p0[0] + p0[1]) + (p0[2] + p0[3]);
            lp1 += (p1[0] + p1[1]) + (p1[2] + p1[3]);
            // truncation-pack to bf16
            const unsigned a0 = (__float_as_uint(p0[0]) >> 16) | (__float_as_uint(p0[1]) & 0xffff0000u);
            const unsigned a1 = (__float_as_uint(p0[2]) >> 16) | (__float_as_uint(p0[3]) & 0xffff0000u);
            const unsigned b0 = (__float_as_uint(p1[0]) >> 16) | (__float_as_uint(p1[1]) & 0xffff0000u);
            const unsigned b1 = (__float_as_uint(p1[2]) >> 16) | (__float_as_uint(p1[3]) & 0xffff0000u);
            *(uint2*)&Ps[wave][l15][kg * 16 + quad * 4]      = make_uint2(a0, a1);
            *(uint2*)&Ps[wave][16 + l15][kg * 16 + quad * 4] = make_uint2(b0, b1);
        }
        const bf16x8 pa0lo = *(const bf16x8*)&Ps[wave][l15][quad * 8];
        const bf16x8 pa0hi = *(const bf16x8*)&Ps[wave][l15][32 + quad * 8];
        const bf16x8 pa1lo = *(const bf16x8*)&Ps[wave][16 + l15][quad * 8];
        const bf16x8 pa1hi = *(const bf16x8*)&Ps[wave][16 + l15][32 + quad * 8];
        const u16* vr0 = Vb + (long)l15 * Nkpad + m0;
        const u16* vr1 = Vb + (long)(16 + l15) * Nkpad + m0;
        const bf16x8 v0lo = *(const bf16x8*)(vr0 + quad * 8);
        const bf16x8 v0hi = *(const bf16x8*)(vr0 + 32 + quad * 8);
        const bf16x8 v1lo = *(const bf16x8*)(vr1 + quad * 8);
        const bf16x8 v1hi = *(const bf16x8*)(vr1 + 32 + quad * 8);
        o00 = MFMA(pa0lo, v0lo, o00); o00 = MFMA(pa0hi, v0hi, o00);
        o01 = MFMA(pa0lo, v1lo, o01); o01 = MFMA(pa0hi, v1hi, o01);
        o10 = MFMA(pa1lo, v0lo, o10); o10 = MFMA(pa1hi, v0hi, o10);
        o11 = MFMA(pa1lo, v1lo, o11); o11 = MFMA(pa1hi, v1hi, o11);
    }

    // lp: reduce across the 4 quad-replicas of each q
    lp0 += __shfl_xor(lp0, 16); lp0 += __shfl_xor(lp0, 32);
    lp1 += __shfl_xor(lp1, 16); lp1 += __shfl_xor(lp1, 32);
    if (quad == 0) {
        const int qa = q0w + l15, qb = q0w + 16 + l15;
        if (qa < Nq) atomicAdd(&pl[(long)bh * Nq + qa], lp0);
        if (qb < Nq) atomicAdd(&pl[(long)bh * Nq + qb], lp1);
    }
    #pragma unroll
    for (int r = 0; r < 4; ++r) {
        const int qA = q0w + quad * 4 + r, qB = qA + 16;
        if (qA < Nq) {
            float* d = &pacc[((long)bh * Nq + qA) * 32];
            atomicAdd(&d[l15], o00[r]); atomicAdd(&d[16 + l15], o01[r]);
        }
        if (qB < Nq) {
            float* d = &pacc[((long)bh * Nq + qB) * 32];
            atomicAdd(&d[l15], o10[r]); atomicAdd(&d[16 + l15], o11[r]);
        }
    }
}

// ---------------------------------------------------------------- fused epilogue: combine + Wm + Wc1(BN,ReLU) + Wc2 + resid
// 16-pos tiles; single pacc/pl read (atomic-combined), zero-after-read for next layer.
__global__ __launch_bounds__(256) void epi_kernel(
    float* __restrict__ pl, float* __restrict__ pacc, float npadf,
    const float* __restrict__ x1,
    const u16* __restrict__ Wm, const float* __restrict__ bm,
    const u16* __restrict__ Wc1, const float* __restrict__ bc1,
    const float* __restrict__ bns, const float* __restrict__ bnsh,
    const u16* __restrict__ Wc2, const float* __restrict__ bc2,
    float* __restrict__ outF, float* __restrict__ outR, int Nq)
{
    __shared__ u16 Xa[16][136];
    __shared__ u16 Xc[16][264];
    __shared__ u16 Xh[16][264];
    const int tid = threadIdx.x;
    const int wid = tid >> 6, lane = tid & 63;
    const int l15 = lane & 15, quad = lane >> 4;
    const int b = blockIdx.y;
    const int p0 = blockIdx.x * 16;

    // ---- phase 1: read combined partials -> Xa ; stage x1 -> Xc[:,0:128]; zero pacc/pl
    {
        const int pos = tid & 15, sub = tid >> 4;      // 16 subs x 8 ch
        const bool own = (p0 + pos < Nq);
        const int pp = own ? p0 + pos : Nq - 1;
        const int h = sub >> 2, d0 = (sub & 3) * 8;
        const int bh = b * 4 + h;
        float* pls = &pl[(long)bh * Nq + pp];
        const float lg = *pls - npadf;                 // pad keys contributed p=1 each
        float* src = &pacc[((long)bh * Nq + pp) * 32 + d0];
        const float4 v0 = *(const float4*)&src[0];
        const float4 v1 = *(const float4*)&src[4];
        if (own) {                                      // zero-after-read (owner only)
            const float4 z = {0.f, 0.f, 0.f, 0.f};
            *(float4*)&src[0] = z; *(float4*)&src[4] = z;
            if ((sub & 3) == 0) *pls = 0.f;
        }
        const float inv = 1.f / lg;
        bf16x8 v;
        v[0] = (short)f2bf(v0.x * inv); v[1] = (short)f2bf(v0.y * inv);
        v[2] = (short)f2bf(v0.z * inv); v[3] = (short)f2bf(v0.w * inv);
        v[4] = (short)f2bf(v1.x * inv); v[5] = (short)f2bf(v1.y * inv);
        v[6] = (short)f2bf(v1.z * inv); v[7] = (short)f2bf(v1.w * inv);
        *(bf16x8*)&Xa[pos][h * 32 + d0] = v;
        bf16x8 y;
        #pragma unroll
        for (int j = 0; j < 8; ++j)
            y[j] = (short)f2bf(x1[((long)b * 128 + sub * 8 + j) * Nq + pp]);
        *(bf16x8*)&Xc[pos][sub * 8] = y;
    }
    __syncthreads();

    // ---- phase 2: m = Wm*add + bm -> Xc[:,128:256]
    {
        f32x4 am[2] = {};
        for (int k0 = 0; k0 < 128; k0 += 32) {
            #pragma unroll
            for (int og = 0; og < 2; ++og) {
                const bf16x8 af = *(const bf16x8*)(Wm + (long)(wid * 32 + og * 16 + l15) * 128 + k0 + quad * 8);
                const bf16x8 bfr = *(const bf16x8*)&Xa[l15][k0 + quad * 8];
                am[og] = MFMA(af, bfr, am[og]);
            }
        }
        #pragma unroll
        for (int og = 0; og < 2; ++og)
            #pragma unroll
            for (int r = 0; r < 4; ++r) {
                const int o = wid * 32 + og * 16 + quad * 4 + r;
                Xc[l15][128 + o] = f2bf(am[og][r] + bm[o]);
            }
    }
    __syncthreads();

    // ---- phase 3: h = relu(bns*(Wc1*[x1;m]+bc1)+bnsh) -> Xh
    {
        f32x4 a1[4] = {};
        for (int k0 = 0; k0 < 256; k0 += 32) {
            #pragma unroll
            for (int og = 0; og < 4; ++og) {
                const bf16x8 af = *(const bf16x8*)(Wc1 + (long)(wid * 64 + og * 16 + l15) * 256 + k0 + quad * 8);
                const bf16x8 bfr = *(const bf16x8*)&Xc[l15][k0 + quad * 8];
                a1[og] = MFMA(af, bfr, a1[og]);
            }
        }
        #pragma unroll
        for (int og = 0; og < 4; ++og)
            #pragma unroll
            for (int r = 0; r < 4; ++r) {
                const int o = wid * 64 + og * 16 + quad * 4 + r;
                const float hv = fmaxf((a1[og][r] + bc1[o]) * bns[o] + bnsh[o], 0.f);
                Xh[l15][o] = f2bf(hv);
            }
    }
    __syncthreads();

    // ---- phase 4: y = Wc2*h + bc2 (+x1 resid) -> outF (+outR raw)
    {
        f32x4 a2[2] = {};
        for (int k0 = 0; k0 < 256; k0 += 32) {
            #pragma unroll
            for (int og = 0; og < 2; ++og) {
                const bf16x8 af = *(const bf16x8*)(Wc2 + (long)(wid * 32 + og * 16 + l15) * 256 + k0 + quad * 8);
                const bf16x8 bfr = *(const bf16x8*)&Xh[l15][k0 + quad * 8];
                a2[og] = MFMA(af, bfr, a2[og]);
            }
        }
        const int p = p0 + l15;
        #pragma unroll
        for (int og = 0; og < 2; ++og)
            #pragma unroll
            for (int r = 0; r < 4; ++r) {
                const int o = wid * 32 + og * 16 + quad * 4 + r;
                if (p < Nq) {
                    const long idx = ((long)b * 128 + o) * Nq + p;
                    const float v = a2[og][r] + bc2[o];
                    outF[idx] = v + x1[idx];
                    if (outR) outR[idx] = v;
                }
            }
    }
}

// ---------------------------------------------------------------- tail1: conv 128->64 (MFMA) + atomic stats
__global__ __launch_bounds__(256) void tail1_kernel(
    const float* __restrict__ X, const u16* __restrict__ W, const float* __restrict__ bias,
    float* __restrict__ Y, float* __restrict__ ps, float* __restrict__ pq, int P)
{
    __shared__ u16 Xt[64][40];
    const int tid = threadIdx.x;
    const int wid = tid >> 6, lane = tid & 63;
    const int l15 = lane & 15, quad = lane >> 4;
    const int b = blockIdx.y;
    const int p0 = blockIdx.x * 64;
    const int sp = tid & 63, cg = tid >> 6;
    f32x4 acc[4] = {};
    for (int k0 = 0; k0 < 128; k0 += 32) {
        bf16x8 st;
        {
            const int pp = (p0 + sp < P) ? p0 + sp : P - 1;
            #pragma unroll
            for (int j = 0; j < 8; ++j)
                st[j] = (short)f2bf(X[((long)b * 128 + k0 + cg * 8 + j) * P + pp]);
        }
        __syncthreads();
        *(bf16x8*)&Xt[sp][cg * 8] = st;
        __syncthreads();
        const bf16x8 af = *(const bf16x8*)(W + (long)(wid * 16 + l15) * 128 + k0 + quad * 8);
        #pragma unroll
        for (int pg = 0; pg < 4; ++pg) {
            const bf16x8 bfr = *(const bf16x8*)&Xt[pg * 16 + l15][quad * 8];
            acc[pg] = MFMA(af, bfr, acc[pg]);
        }
    }
    float sums[4] = {}, sq[4] = {};
    #pragma unroll
    for (int pg = 0; pg < 4; ++pg)
        #pragma unroll
        for (int r = 0; r < 4; ++r) {
            const int o = wid * 16 + quad * 4 + r;
            const int p = p0 + pg * 16 + l15;
            if (p < P) {
                const float v = acc[pg][r] + bias[o];
                Y[((long)b * 64 + o) * P + p] = v;
                sums[r] += v; sq[r] += v * v;
            }
        }
    #pragma unroll
    for (int mk = 1; mk < 16; mk <<= 1)
        #pragma unroll
        for (int r = 0; r < 4; ++r) { sums[r] += __shfl_xor(sums[r], mk); sq[r] += __shfl_xor(sq[r], mk); }
    if (l15 == 0)
        #pragma unroll
        for (int r = 0; r < 4; ++r) {
            const int o = wid * 16 + quad * 4 + r;
            atomicAdd(&ps[b * 64 + o], sums[r]);
            atomicAdd(&pq[b * 64 + o], sq[r]);
        }
}

// ---------------------------------------------------------------- tail (parallel): norm(prev) -> conv -> stats
template<int CI, int CO, bool STATS>
__global__ __launch_bounds__(256) void tail_par(
    const float* __restrict__ xraw, const float* __restrict__ ps, const float* __restrict__ pq,
    const float* __restrict__ sc, const float* __restrict__ sh,
    const float* __restrict__ W, const float* __restrict__ bias,
    float* __restrict__ ps2, float* __restrict__ pq2, float* __restrict__ yout, int P)
{
    __shared__ float k1s[CI], k2s[CI], Wl[CO * CI];
    __shared__ float sS[CO], sQ[CO];
    const int tid = threadIdx.x;
    const int b = blockIdx.y;
    const int pos = tid >> 2, g = tid & 3;     // quad-split: 64 pos x 4 c-groups
    for (int i = tid; i < CO * CI; i += 256) Wl[i] = W[i];
    if (tid < CI) {
        const float S = ps[b * CI + tid], Q2 = pq[b * CI + tid];
        const float mu = S / P, var = Q2 / P - mu * mu;
        const float rs = rsqrtf(var + 1e-3f);
        k1s[tid] = rs * sc[tid];
        k2s[tid] = sh[tid] - mu * rs * sc[tid];
    }
    if (STATS && tid < CO) { sS[tid] = 0.f; sQ[tid] = 0.f; }
    __syncthreads();

    const int p = blockIdx.x * 64 + pos;
    const bool valid = p < P;
    const int pp = valid ? p : P - 1;
    float acc[CO] = {};
    constexpr int CG = CI / 4;
    #pragma unroll
    for (int i = 0; i < CG; ++i) {
        const int c = g * CG + i;
        const float xn = fmaxf(xraw[((long)b * CI + c) * P + pp] * k1s[c] + k2s[c], 0.f);
        #pragma unroll
        for (int o = 0; o < CO; ++o) acc[o] += Wl[o * CI + c] * xn;
    }
    #pragma unroll
    for (int o = 0; o < CO; ++o) {
        acc[o] += __shfl_xor(acc[o], 1);
        acc[o] += __shfl_xor(acc[o], 2);
        acc[o] += bias[o];
    }
    if (valid) {
        if (CO >= 4) {
            constexpr int OG = CO / 4;
            #pragma unroll
            for (int i = 0; i < OG; ++i) {
                const int o = g * OG + i;
                yout[((long)b * CO + o) * P + p] = acc[o];
            }
        } else if (g == 0) {
            yout[(long)b * P + p] = acc[0];
        }
    }
    if (STATS) {
        float sv[CO], qv[CO];
        #pragma unroll
        for (int o = 0; o < CO; ++o) {
            const float v = (g == 0 && valid) ? acc[o] : 0.f;
            sv[o] = v; qv[o] = v * v;
        }
        #pragma unroll
        for (int mk = 1; mk < 64; mk <<= 1)
            #pragma unroll
            for (int o = 0; o < CO; ++o) { sv[o] += __shfl_xor(sv[o], mk); qv[o] += __shfl_xor(qv[o], mk); }
        if ((tid & 63) == 0)
            #pragma unroll
            for (int o = 0; o < CO; ++o) { atomicAdd(&sS[o], sv[o]); atomicAdd(&sQ[o], qv[o]); }
        __syncthreads();
        if (tid < CO) { atomicAdd(&ps2[b * CO + tid], sS[tid]); atomicAdd(&pq2[b * CO + tid], sQ[tid]); }
    }
}

// ================================================================ host
extern "C" void kernel_launch(void* const* d_in, const int* in_sizes, int n_in,
                              void* d_out, int out_size, void* d_ws, size_t ws_size,
                              hipStream_t stream)
{
    const float* dX   = (const float*)d_in[1];
    const float* fpX  = (const float*)d_in[2];
    const float* lgin = (const float*)d_in[3];
    const float* Wq = (const float*)d_in[4];  const float* bq = (const float*)d_in[5];
    const float* Wk = (const float*)d_in[6];  const float* bk = (const float*)d_in[7];
    const float* Wv = (const float*)d_in[8];  const float* bv = (const float*)d_in[9];
    const float* Wm = (const float*)d_in[10]; const float* bm = (const float*)d_in[11];
    const float* Wc1= (const float*)d_in[12]; const float* bc1= (const float*)d_in[13];
    const float* bns= (const float*)d_in[14]; const float* bnsh=(const float*)d_in[15];
    const float* Wc2= (const float*)d_in[16]; const float* bc2= (const float*)d_in[17];
    const float* iW1= (const float*)d_in[18]; const float* ib1= (const float*)d_in[19];
    const float* s1 = (const float*)d_in[20]; const float* h1 = (const float*)d_in[21];
    const float* iW2= (const float*)d_in[22]; const float* ib2= (const float*)d_in[23];
    const float* s2 = (const float*)d_in[24]; const float* h2 = (const float*)d_in[25];
    const float* iW3= (const float*)d_in[26]; const float* ib3= (const float*)d_in[27];
    const float* s3 = (const float*)d_in[28]; const float* h3 = (const float*)d_in[29];
    const float* iW4= (const float*)d_in[30]; const float* ib4= (const float*)d_in[31];

    float* out_d      = (float*)d_out;                 // [2,128,6000]
    float* out_logits = out_d + (long)B_ * C_ * N_;    // [2,6000]

    float* f = (float*)d_ws;
    long off = 0;
    auto alloc = [&](long n) { float* p = f + off; off += n; return p; };
    float* featA = alloc(384000);
    float* featB = alloc(384000);
    float* q16f  = alloc(800000);    // Q16 [8][Nq][32] u16
    float* k16f  = alloc(800000);    // K16 [8][Nkpad][32] u16
    float* v16f  = alloc(1200000);   // V16 [8][48][Nkpad] u16
    float* xb    = alloc(1536000);
    float* x1raw = alloc(768000);
    float* x2raw = alloc(192000);
    float* x3raw = alloc(48000);
    float* pacc  = alloc(1536000);   // [8][Nqmax=6000][32], atomic-combined
    float* plb   = alloc(48000);     // [8][Nqmax]  (contiguous after pacc for one-shot zero)
    float* zst   = alloc(512);       // stats accumulators (zeroed by prep)
    float* wreg  = alloc(250000);
    (void)ws_size; (void)in_sizes; (void)n_in; (void)out_size;

    float* ps1 = zst;        float* pq1 = zst + 128;
    float* ps2 = zst + 256;  float* pq2 = zst + 288;
    float* ps3 = zst + 320;  float* pq3 = zst + 328;

    u16* wq_h  = (u16*)wreg;
    u16* wk_h  = wq_h + 49152;
    u16* wv_h  = wk_h + 49152;
    u16* wm_h  = wv_h + 49152;
    u16* wc1_h = wm_h + 49152;
    u16* wc2_h = wc1_h + 196608;
    u16* w1_h  = wc2_h + 98304;

    u16* Q16 = (u16*)q16f;
    u16* K16 = (u16*)k16f;
    u16* V16 = (u16*)v16f;

    prep_kernel<<<dim3(768), 256, 0, stream>>>(Wq, Wk, Wv, Wm, Wc1, Wc2, iW1,
                                               wq_h, wk_h, wv_h, wm_h, wc1_h, wc2_h, w1_h,
                                               zst, pacc, 1536000L + 48000L);

    auto layer = [&](const float* x1, const float* x2, int Nq, int Nk,
                     const float* maskl, int li, int KS, int chunkLen,
                     float* outF, float* outR) {
        const int Nkpad = KS * chunkLen;                 // >= Nk, chunkLen mult of 64
        const float npadf = maskl ? 0.f : (float)(Nkpad - Nk);
        qkv_kernel<<<dim3((max(Nq, Nkpad) + 63) / 64, 6, B_), 256, 0, stream>>>(
            x1, x2, Nq, Nk, Nkpad,
            wq_h + (long)li * 16384, wk_h + (long)li * 16384, wv_h + (long)li * 16384,
            bq + li * 128, bk + li * 128, bv + li * 128, Q16, K16, V16);
        const int qblocks = (Nq + 127) / 128;
        if (maskl)
            attn_partial<true><<<dim3(qblocks * KS * 8), 256, 0, stream>>>(
                Q16, K16, V16, maskl, plb, pacc, Nq, Nk, Nkpad, KS, chunkLen);
        else
            attn_partial<false><<<dim3(qblocks * KS * 8), 256, 0, stream>>>(
                Q16, K16, V16, nullptr, plb, pacc, Nq, Nk, Nkpad, KS, chunkLen);
        epi_kernel<<<dim3((Nq + 15) / 16, B_), 256, 0, stream>>>(
            plb, pacc, npadf, x1,
            wm_h + (long)li * 16384, bm + li * 128,
            wc1_h + (long)li * 65536, bc1 + li * 256, bns + li * 256, bnsh + li * 256,
            wc2_h + (long)li * 32768, bc2 + li * 128,
            outF, outR, Nq);
    };

    layer(fpX,   dX,    M_, N_, lgin,    0, 8, 768, featA, nullptr);   // Nkpad 6144
    layer(featA, featA, M_, M_, nullptr, 1, 8, 192, featB, nullptr);   // Nkpad 1536, npad 36
    layer(dX,    featB, N_, M_, nullptr, 2, 2, 768, out_d, xb);        // Nkpad 1536, npad 36

    tail1_kernel<<<dim3((N_ + 63) / 64, B_), 256, 0, stream>>>(xb, w1_h, ib1, x1raw, ps1, pq1, N_);
    tail_par<64, 16, true><<<dim3((N_ + 63) / 64, B_), 256, 0, stream>>>(
        x1raw, ps1, pq1, s1, h1, iW2, ib2, ps2, pq2, x2raw, N_);
    tail_par<16, 4, true><<<dim3((N_ + 63) / 64, B_), 256, 0, stream>>>(
        x2raw, ps2, pq2, s2, h2, iW3, ib3, ps3, pq3, x3raw, N_);
    tail_par<4, 1, false><<<dim3((N_ + 63) / 64, B_), 256, 0, stream>>>(
        x3raw, ps3, pq3, s3, h3, iW4, ib4, nullptr, nullptr, out_logits, N_);
}

// Round 14
// 351.547 us; speedup vs baseline: 1.0442x; 1.0442x over previous
//
#include <hip/hip_runtime.h>
#include <math.h>

#define B_  2
#define C_  128
#define N_  6000
#define M_  1500
#define H_  4
#define DH_ 32

typedef __attribute__((ext_vector_type(8))) short bf16x8;   // 8 bf16 = 4 VGPRs
typedef __attribute__((ext_vector_type(4))) float f32x4;
typedef unsigned short u16;

static __device__ __forceinline__ u16 f2bf(float x) {
    unsigned u = __float_as_uint(x);
    return (u16)((u + 0x7fffu + ((u >> 16) & 1u)) >> 16);   // RNE
}
#define MFMA(a,b,c) __builtin_amdgcn_mfma_f32_16x16x32_bf16((a),(b),(c),0,0,0)
// exp2-domain softmax: Q pre-scaled by (1/sqrt(32))*log2(e) in qkv_kernel
#define INVS2 (0.17677669529663687f * 1.4426950408889634f)

// ---------------------------------------------------------------- prep: weights->bf16, zero stats
__global__ __launch_bounds__(256) void prep_kernel(
    const float* __restrict__ Wq, const float* __restrict__ Wk, const float* __restrict__ Wv,
    const float* __restrict__ Wm, const float* __restrict__ Wc1, const float* __restrict__ Wc2,
    const float* __restrict__ iW1,
    u16* __restrict__ wq, u16* __restrict__ wk, u16* __restrict__ wv, u16* __restrict__ wm,
    u16* __restrict__ wc1, u16* __restrict__ wc2, u16* __restrict__ w1,
    float* __restrict__ zstats)
{
    long i = (long)blockIdx.x * 256 + threadIdx.x;
    if (i < 512)    zstats[i] = 0.f;
    if (i < 49152)  { wq[i] = f2bf(Wq[i]); wk[i] = f2bf(Wk[i]);
                      wv[i] = f2bf(Wv[i]); wm[i] = f2bf(Wm[i]); }
    if (i < 196608) wc1[i] = f2bf(Wc1[i]);
    if (i < 98304)  wc2[i] = f2bf(Wc2[i]);
    if (i < 8192)   w1[i]  = f2bf(iW1[i]);
}

// ---------------------------------------------------------------- fused q/k/v conv (MFMA, CIN=128)
// Layouts: Q16 [bh][Nq][32] (pre-scaled by INVS2); K16 [bh][Nkpad][32] (pads zeroed);
//          V16 [bh][48][Nkpad]: rows 0-31 = V dh (pads zeroed), rows 32-47 zero.
__global__ __launch_bounds__(256) void qkv_kernel(
    const float* __restrict__ x1, const float* __restrict__ x2, int Pq, int Pk, int Pkpad,
    const u16* __restrict__ wq, const u16* __restrict__ wk, const u16* __restrict__ wv,
    const float* __restrict__ bq, const float* __restrict__ bk, const float* __restrict__ bv,
    u16* __restrict__ Q16, u16* __restrict__ K16, u16* __restrict__ V16)
{
    __shared__ u16 Xt[64][40];      // [pos][cin-chunk], row 80B
    const int tid = threadIdx.x;
    const int wid = tid >> 6, lane = tid & 63;
    const int l15 = lane & 15, quad = lane >> 4;
    const int job = blockIdx.y >> 1, ot = blockIdx.y & 1;
    const int b = blockIdx.z;
    const int p0 = blockIdx.x * 64;
    const float* X; const u16* W; const float* bias; int P;
    if (job == 0)      { X = x1; W = wq; bias = bq; P = Pq; }
    else if (job == 1) { X = x2; W = wk; bias = bk; P = Pk; }
    else               { X = x2; W = wv; bias = bv; P = Pk; }
    const int Plim = (job == 0) ? Pq : Pkpad;
    if (p0 < Plim) {
        const long xoff = (long)b * C_ * P;
        const int sp = tid & 63, cg = tid >> 6;
        f32x4 acc[4] = {};
        if (p0 < P) {
            for (int k0 = 0; k0 < 128; k0 += 32) {
                bf16x8 st;
                const int pp = (p0 + sp < P) ? p0 + sp : P - 1;
                #pragma unroll
                for (int j = 0; j < 8; ++j)
                    st[j] = (short)f2bf(X[xoff + (long)(k0 + cg * 8 + j) * P + pp]);
                __syncthreads();
                *(bf16x8*)&Xt[sp][cg * 8] = st;
                __syncthreads();
                const bf16x8 af = *(const bf16x8*)(W + (long)(ot * 64 + wid * 16 + l15) * 128 + k0 + quad * 8);
                #pragma unroll
                for (int pg = 0; pg < 4; ++pg) {
                    const bf16x8 bfr = *(const bf16x8*)&Xt[pg * 16 + l15][quad * 8];
                    acc[pg] = MFMA(af, bfr, acc[pg]);
                }
            }
        }
        #pragma unroll
        for (int pg = 0; pg < 4; ++pg)
            #pragma unroll
            for (int r = 0; r < 4; ++r) {
                const int o = ot * 64 + wid * 16 + quad * 4 + r;
                const int p = p0 + pg * 16 + l15;
                if (p >= Plim) continue;
                if (job == 0) {
                    if (p < Pq)
                        Q16[((long)(b * 4 + (o >> 5)) * Pq + p) * 32 + (o & 31)] =
                            f2bf((acc[pg][r] + bias[o]) * INVS2);
                } else {
                    const u16 v = (p < P) ? f2bf(acc[pg][r] + bias[o]) : (u16)0;
                    if (job == 1)
                        K16[((long)(b * 4 + (o >> 5)) * Pkpad + p) * 32 + (o & 31)] = v;
                    else
                        V16[((long)(b * 4 + (o >> 5)) * 48 + (o & 31)) * Pkpad + p] = v;
                }
            }
        if (job == 2) {     // rows 32..47 zero (B-frag reads may overrun into them)
            for (int e = tid; e < 2048; e += 256) {
                const int which = e >> 10;
                const int row = 32 + ((e >> 6) & 15);
                const int col = p0 + (e & 63);
                if (col < Pkpad)
                    V16[((long)(b * 4 + ot * 2 + which) * 48 + row) * Pkpad + col] = (u16)0;
            }
        }
    }
}

// ---------------------------------------------------------------- flash attention (MFMA, S^T, full tiles)
// R14 = R12 structure (KS-split pacc, plain stores) + R13 core (lp in VALU, no lp-MFMA).
template<bool MASKED>
__global__ __launch_bounds__(256) void attn_partial(
    const u16* __restrict__ Q16, const u16* __restrict__ K16, const u16* __restrict__ V16,
    const float* __restrict__ lgin,
    float* __restrict__ pl, float* __restrict__ pacc,
    int Nq, int Nk, int Nkpad, int KS, int chunkLen, int npad)
{
    __shared__ u16 Ps[4][32][72];   // per-wave P round-trip
    const int tid  = threadIdx.x;
    const int wave = tid >> 6, lane = tid & 63;
    const int l15  = lane & 15, quad = lane >> 4;
    const int bid  = blockIdx.x;
    const int bh   = bid & 7, rest = bid >> 3;
    const int split = rest % KS, qblk = rest / KS;
    const int b = bh >> 2;
    const int q0w = qblk * 128 + wave * 32;

    const u16* Qb = Q16 + (long)bh * Nq * 32;
    const u16* Kb = K16 + (long)bh * Nkpad * 32;
    const u16* Vb = V16 + (long)(bh * 48) * Nkpad;

    const int qq0 = min(q0w + l15, Nq - 1);
    const int qq1 = min(q0w + 16 + l15, Nq - 1);
    const bf16x8 qa0 = *(const bf16x8*)(Qb + (long)qq0 * 32 + quad * 8);
    const bf16x8 qa1 = *(const bf16x8*)(Qb + (long)qq1 * 32 + quad * 8);

    f32x4 o00={0,0,0,0}, o01={0,0,0,0}, o10={0,0,0,0}, o11={0,0,0,0};
    float lp0 = 0.f, lp1 = 0.f;
    const f32x4 z4 = {0,0,0,0};

    const int kbeg = split * chunkLen;
    const int kend = kbeg + chunkLen;        // full tiles (pads zeroed)

    for (int m0 = kbeg; m0 < kend; m0 += 64) {
        f32x4 sa0[4], sa1[4];
        #pragma unroll
        for (int kg = 0; kg < 4; ++kg) {
            const bf16x8 ka = *(const bf16x8*)(Kb + (long)(m0 + kg * 16 + l15) * 32 + quad * 8);
            sa0[kg] = MFMA(ka, qa0, z4);
            sa1[kg] = MFMA(ka, qa1, z4);
        }
        #pragma unroll
        for (int kg = 0; kg < 4; ++kg) {
            float p0[4], p1[4];
            if (MASKED) {
                const int kbase = m0 + kg * 16 + quad * 4;
                const float4 mv = *(const float4*)&lgin[(long)b * Nk + min(kbase, Nk - 4)];
                const float* mr = (const float*)&mv;
                #pragma unroll
                for (int r = 0; r < 4; ++r) {
                    const bool good = (kbase + r < Nk) && (mr[r] > 0.f);
                    p0[r] = good ? exp2f(sa0[kg][r]) : 0.f;
                    p1[r] = good ? exp2f(sa1[kg][r]) : 0.f;
                }
            } else {
                #pragma unroll
                for (int r = 0; r < 4; ++r) { p0[r] = exp2f(sa0[kg][r]); p1[r] = exp2f(sa1[kg][r]); }
            }
            lp0 += (p0[0] + p0[1]) + (p0[2] + p0[3]);
            lp1 += (p1[0] + p1[1]) + (p1[2] + p1[3]);
            // truncation-pack to bf16
            const unsigned a0 = (__float_as_uint(p0[0]) >> 16) | (__float_as_uint(p0[1]) & 0xffff0000u);
            const unsigned a1 = (__float_as_uint(p0[2]) >> 16) | (__float_as_uint(p0[3]) & 0xffff0000u);
            const unsigned b0 = (__float_as_uint(p1[0]) >> 16) | (__float_as_uint(p1[1]) & 0xffff0000u);
            const unsigned b1 = (__float_as_uint(p1[2]) >> 16) | (__float_as_uint(p1[3]) & 0xffff0000u);
            *(uint2*)&Ps[wave][l15][kg * 16 + quad * 4]      = make_uint2(a0, a1);
            *(uint2*)&Ps[wave][16 + l15][kg * 16 + quad * 4] = make_uint2(b0, b1);
        }
        const bf16x8 pa0lo = *(const bf16x8*)&Ps[wave][l15][quad * 8];
        const bf16x8 pa0hi = *(const bf16x8*)&Ps[wave][l15][32 + quad * 8];
        const bf16x8 pa1lo = *(const bf16x8*)&Ps[wave][16 + l15][quad * 8];
        const bf16x8 pa1hi = *(const bf16x8*)&Ps[wave][16 + l15][32 + quad * 8];
        const u16* vr0 = Vb + (long)l15 * Nkpad + m0;
        const u16* vr1 = Vb + (long)(16 + l15) * Nkpad + m0;
        const bf16x8 v0lo = *(const bf16x8*)(vr0 + quad * 8);
        const bf16x8 v0hi = *(const bf16x8*)(vr0 + 32 + quad * 8);
        const bf16x8 v1lo = *(const bf16x8*)(vr1 + quad * 8);
        const bf16x8 v1hi = *(const bf16x8*)(vr1 + 32 + quad * 8);
        o00 = MFMA(pa0lo, v0lo, o00); o00 = MFMA(pa0hi, v0hi, o00);
        o01 = MFMA(pa0lo, v1lo, o01); o01 = MFMA(pa0hi, v1hi, o01);
        o10 = MFMA(pa1lo, v0lo, o10); o10 = MFMA(pa1hi, v0hi, o10);
        o11 = MFMA(pa1lo, v1lo, o11); o11 = MFMA(pa1hi, v1hi, o11);
    }

    // lp: reduce across the 4 quad-replicas of each q
    lp0 += __shfl_xor(lp0, 16); lp0 += __shfl_xor(lp0, 32);
    lp1 += __shfl_xor(lp1, 16); lp1 += __shfl_xor(lp1, 32);

    const long base = (long)bh * KS + split;
    const float fn = (split == KS - 1) ? (float)npad : 0.f;   // pad keys contributed p=1 each
    if (quad == 0) {
        const int qa = q0w + l15, qb = q0w + 16 + l15;
        if (qa < Nq) pl[base * Nq + qa] = lp0 - fn;
        if (qb < Nq) pl[base * Nq + qb] = lp1 - fn;
    }
    #pragma unroll
    for (int r = 0; r < 4; ++r) {
        const int qA = q0w + quad * 4 + r, qB = qA + 16;
        if (qA < Nq) { float* d = &pacc[((long)base * Nq + qA) * 32]; d[l15] = o00[r]; d[16 + l15] = o01[r]; }
        if (qB < Nq) { float* d = &pacc[((long)base * Nq + qB) * 32]; d[l15] = o10[r]; d[16 + l15] = o11[r]; }
    }
}

// ---------------------------------------------------------------- fused epilogue: combine + Wm + Wc1(BN,ReLU) + Wc2 + resid
__global__ __launch_bounds__(256) void epi_kernel(
    const float* __restrict__ pl, const float* __restrict__ pacc, int KS,
    const float* __restrict__ x1,
    const u16* __restrict__ Wm, const float* __restrict__ bm,
    const u16* __restrict__ Wc1, const float* __restrict__ bc1,
    const float* __restrict__ bns, const float* __restrict__ bnsh,
    const u16* __restrict__ Wc2, const float* __restrict__ bc2,
    float* __restrict__ outF, float* __restrict__ outR, int Nq)
{
    __shared__ u16 Xa[32][136];
    __shared__ u16 Xc[32][264];
    __shared__ u16 Xh[32][264];
    const int tid = threadIdx.x;
    const int wid = tid >> 6, lane = tid & 63;
    const int l15 = lane & 15, quad = lane >> 4;
    const int b = blockIdx.y;
    const int p0 = blockIdx.x * 32;

    {
        const int pos = tid & 31, sub = tid >> 5;
        const int pp = (p0 + pos < Nq) ? p0 + pos : Nq - 1;
        const int h = sub >> 1, d0 = (sub & 1) * 16;
        const int bh = b * 4 + h;
        float lg = 0.f, acc[16];
        #pragma unroll
        for (int i = 0; i < 16; ++i) acc[i] = 0.f;
        for (int s = 0; s < KS; ++s) {
            const long base = (long)bh * KS + s;
            lg += pl[base * Nq + pp];
            const float* src = &pacc[(base * Nq + pp) * 32 + d0];
            #pragma unroll
            for (int i = 0; i < 4; ++i) {
                const float4 v = *(const float4*)&src[i * 4];
                acc[i*4+0] += v.x; acc[i*4+1] += v.y; acc[i*4+2] += v.z; acc[i*4+3] += v.w;
            }
        }
        const float inv = 1.f / lg;
        bf16x8 v0, v1;
        #pragma unroll
        for (int i = 0; i < 8; ++i) { v0[i] = (short)f2bf(acc[i] * inv); v1[i] = (short)f2bf(acc[8 + i] * inv); }
        const int c0 = h * 32 + (sub & 1) * 16;
        *(bf16x8*)&Xa[pos][c0] = v0;
        *(bf16x8*)&Xa[pos][c0 + 8] = v1;
        bf16x8 y0, y1;
        #pragma unroll
        for (int j = 0; j < 8; ++j) {
            y0[j] = (short)f2bf(x1[((long)b * 128 + sub * 16 + j) * Nq + pp]);
            y1[j] = (short)f2bf(x1[((long)b * 128 + sub * 16 + 8 + j) * Nq + pp]);
        }
        *(bf16x8*)&Xc[pos][sub * 16] = y0;
        *(bf16x8*)&Xc[pos][sub * 16 + 8] = y1;
    }
    __syncthreads();

    {
        f32x4 am[2][2] = {};
        for (int k0 = 0; k0 < 128; k0 += 32) {
            #pragma unroll
            for (int og = 0; og < 2; ++og) {
                const bf16x8 af = *(const bf16x8*)(Wm + (long)(wid * 32 + og * 16 + l15) * 128 + k0 + quad * 8);
                #pragma unroll
                for (int pg = 0; pg < 2; ++pg) {
                    const bf16x8 bfr = *(const bf16x8*)&Xa[pg * 16 + l15][k0 + quad * 8];
                    am[og][pg] = MFMA(af, bfr, am[og][pg]);
                }
            }
        }
        #pragma unroll
        for (int og = 0; og < 2; ++og)
            #pragma unroll
            for (int pg = 0; pg < 2; ++pg)
                #pragma unroll
                for (int r = 0; r < 4; ++r) {
                    const int o = wid * 32 + og * 16 + quad * 4 + r;
                    Xc[pg * 16 + l15][128 + o] = f2bf(am[og][pg][r] + bm[o]);
                }
    }
    __syncthreads();

    {
        f32x4 a1[4][2] = {};
        for (int k0 = 0; k0 < 256; k0 += 32) {
            #pragma unroll
            for (int og = 0; og < 4; ++og) {
                const bf16x8 af = *(const bf16x8*)(Wc1 + (long)(wid * 64 + og * 16 + l15) * 256 + k0 + quad * 8);
                #pragma unroll
                for (int pg = 0; pg < 2; ++pg) {
                    const bf16x8 bfr = *(const bf16x8*)&Xc[pg * 16 + l15][k0 + quad * 8];
                    a1[og][pg] = MFMA(af, bfr, a1[og][pg]);
                }
            }
        }
        #pragma unroll
        for (int og = 0; og < 4; ++og)
            #pragma unroll
            for (int pg = 0; pg < 2; ++pg)
                #pragma unroll
                for (int r = 0; r < 4; ++r) {
                    const int o = wid * 64 + og * 16 + quad * 4 + r;
                    const float hv = fmaxf((a1[og][pg][r] + bc1[o]) * bns[o] + bnsh[o], 0.f);
                    Xh[pg * 16 + l15][o] = f2bf(hv);
                }
    }
    __syncthreads();

    {
        f32x4 a2[2][2] = {};
        for (int k0 = 0; k0 < 256; k0 += 32) {
            #pragma unroll
            for (int og = 0; og < 2; ++og) {
                const bf16x8 af = *(const bf16x8*)(Wc2 + (long)(wid * 32 + og * 16 + l15) * 256 + k0 + quad * 8);
                #pragma unroll
                for (int pg = 0; pg < 2; ++pg) {
                    const bf16x8 bfr = *(const bf16x8*)&Xh[pg * 16 + l15][k0 + quad * 8];
                    a2[og][pg] = MFMA(af, bfr, a2[og][pg]);
                }
            }
        }
        #pragma unroll
        for (int og = 0; og < 2; ++og)
            #pragma unroll
            for (int pg = 0; pg < 2; ++pg)
                #pragma unroll
                for (int r = 0; r < 4; ++r) {
                    const int o = wid * 32 + og * 16 + quad * 4 + r;
                    const int p = p0 + pg * 16 + l15;
                    if (p < Nq) {
                        const long idx = ((long)b * 128 + o) * Nq + p;
                        const float v = a2[og][pg][r] + bc2[o];
                        outF[idx] = v + x1[idx];
                        if (outR) outR[idx] = v;
                    }
                }
    }
}

// ---------------------------------------------------------------- tail1: conv 128->64 (MFMA) + atomic stats
__global__ __launch_bounds__(256) void tail1_kernel(
    const float* __restrict__ X, const u16* __restrict__ W, const float* __restrict__ bias,
    float* __restrict__ Y, float* __restrict__ ps, float* __restrict__ pq, int P)
{
    __shared__ u16 Xt[64][40];
    const int tid = threadIdx.x;
    const int wid = tid >> 6, lane = tid & 63;
    const int l15 = lane & 15, quad = lane >> 4;
    const int b = blockIdx.y;
    const int p0 = blockIdx.x * 64;
    const int sp = tid & 63, cg = tid >> 6;
    f32x4 acc[4] = {};
    for (int k0 = 0; k0 < 128; k0 += 32) {
        bf16x8 st;
        {
            const int pp = (p0 + sp < P) ? p0 + sp : P - 1;
            #pragma unroll
            for (int j = 0; j < 8; ++j)
                st[j] = (short)f2bf(X[((long)b * 128 + k0 + cg * 8 + j) * P + pp]);
        }
        __syncthreads();
        *(bf16x8*)&Xt[sp][cg * 8] = st;
        __syncthreads();
        const bf16x8 af = *(const bf16x8*)(W + (long)(wid * 16 + l15) * 128 + k0 + quad * 8);
        #pragma unroll
        for (int pg = 0; pg < 4; ++pg) {
            const bf16x8 bfr = *(const bf16x8*)&Xt[pg * 16 + l15][quad * 8];
            acc[pg] = MFMA(af, bfr, acc[pg]);
        }
    }
    float sums[4] = {}, sq[4] = {};
    #pragma unroll
    for (int pg = 0; pg < 4; ++pg)
        #pragma unroll
        for (int r = 0; r < 4; ++r) {
            const int o = wid * 16 + quad * 4 + r;
            const int p = p0 + pg * 16 + l15;
            if (p < P) {
                const float v = acc[pg][r] + bias[o];
                Y[((long)b * 64 + o) * P + p] = v;
                sums[r] += v; sq[r] += v * v;
            }
        }
    #pragma unroll
    for (int mk = 1; mk < 16; mk <<= 1)
        #pragma unroll
        for (int r = 0; r < 4; ++r) { sums[r] += __shfl_xor(sums[r], mk); sq[r] += __shfl_xor(sq[r], mk); }
    if (l15 == 0)
        #pragma unroll
        for (int r = 0; r < 4; ++r) {
            const int o = wid * 16 + quad * 4 + r;
            atomicAdd(&ps[b * 64 + o], sums[r]);
            atomicAdd(&pq[b * 64 + o], sq[r]);
        }
}

// ---------------------------------------------------------------- tail (parallel): norm(prev) -> conv -> stats
template<int CI, int CO, bool STATS>
__global__ __launch_bounds__(256) void tail_par(
    const float* __restrict__ xraw, const float* __restrict__ ps, const float* __restrict__ pq,
    const float* __restrict__ sc, const float* __restrict__ sh,
    const float* __restrict__ W, const float* __restrict__ bias,
    float* __restrict__ ps2, float* __restrict__ pq2, float* __restrict__ yout, int P)
{
    __shared__ float k1s[CI], k2s[CI], Wl[CO * CI];
    __shared__ float sS[CO], sQ[CO];
    const int tid = threadIdx.x;
    const int b = blockIdx.y;
    const int pos = tid >> 2, g = tid & 3;     // quad-split: 64 pos x 4 c-groups
    for (int i = tid; i < CO * CI; i += 256) Wl[i] = W[i];
    if (tid < CI) {
        const float S = ps[b * CI + tid], Q2 = pq[b * CI + tid];
        const float mu = S / P, var = Q2 / P - mu * mu;
        const float rs = rsqrtf(var + 1e-3f);
        k1s[tid] = rs * sc[tid];
        k2s[tid] = sh[tid] - mu * rs * sc[tid];
    }
    if (STATS && tid < CO) { sS[tid] = 0.f; sQ[tid] = 0.f; }
    __syncthreads();

    const int p = blockIdx.x * 64 + pos;
    const bool valid = p < P;
    const int pp = valid ? p : P - 1;
    float acc[CO] = {};
    constexpr int CG = CI / 4;
    #pragma unroll
    for (int i = 0; i < CG; ++i) {
        const int c = g * CG + i;
        const float xn = fmaxf(xraw[((long)b * CI + c) * P + pp] * k1s[c] + k2s[c], 0.f);
        #pragma unroll
        for (int o = 0; o < CO; ++o) acc[o] += Wl[o * CI + c] * xn;
    }
    #pragma unroll
    for (int o = 0; o < CO; ++o) {
        acc[o] += __shfl_xor(acc[o], 1);
        acc[o] += __shfl_xor(acc[o], 2);
        acc[o] += bias[o];
    }
    if (valid) {
        if (CO >= 4) {
            constexpr int OG = CO / 4;
            #pragma unroll
            for (int i = 0; i < OG; ++i) {
                const int o = g * OG + i;
                yout[((long)b * CO + o) * P + p] = acc[o];
            }
        } else if (g == 0) {
            yout[(long)b * P + p] = acc[0];
        }
    }
    if (STATS) {
        float sv[CO], qv[CO];
        #pragma unroll
        for (int o = 0; o < CO; ++o) {
            const float v = (g == 0 && valid) ? acc[o] : 0.f;
            sv[o] = v; qv[o] = v * v;
        }
        #pragma unroll
        for (int mk = 1; mk < 64; mk <<= 1)
            #pragma unroll
            for (int o = 0; o < CO; ++o) { sv[o] += __shfl_xor(sv[o], mk); qv[o] += __shfl_xor(qv[o], mk); }
        if ((tid & 63) == 0)
            #pragma unroll
            for (int o = 0; o < CO; ++o) { atomicAdd(&sS[o], sv[o]); atomicAdd(&sQ[o], qv[o]); }
        __syncthreads();
        if (tid < CO) { atomicAdd(&ps2[b * CO + tid], sS[tid]); atomicAdd(&pq2[b * CO + tid], sQ[tid]); }
    }
}

// ================================================================ host
extern "C" void kernel_launch(void* const* d_in, const int* in_sizes, int n_in,
                              void* d_out, int out_size, void* d_ws, size_t ws_size,
                              hipStream_t stream)
{
    const float* dX   = (const float*)d_in[1];
    const float* fpX  = (const float*)d_in[2];
    const float* lgin = (const float*)d_in[3];
    const float* Wq = (const float*)d_in[4];  const float* bq = (const float*)d_in[5];
    const float* Wk = (const float*)d_in[6];  const float* bk = (const float*)d_in[7];
    const float* Wv = (const float*)d_in[8];  const float* bv = (const float*)d_in[9];
    const float* Wm = (const float*)d_in[10]; const float* bm = (const float*)d_in[11];
    const float* Wc1= (const float*)d_in[12]; const float* bc1= (const float*)d_in[13];
    const float* bns= (const float*)d_in[14]; const float* bnsh=(const float*)d_in[15];
    const float* Wc2= (const float*)d_in[16]; const float* bc2= (const float*)d_in[17];
    const float* iW1= (const float*)d_in[18]; const float* ib1= (const float*)d_in[19];
    const float* s1 = (const float*)d_in[20]; const float* h1 = (const float*)d_in[21];
    const float* iW2= (const float*)d_in[22]; const float* ib2= (const float*)d_in[23];
    const float* s2 = (const float*)d_in[24]; const float* h2 = (const float*)d_in[25];
    const float* iW3= (const float*)d_in[26]; const float* ib3= (const float*)d_in[27];
    const float* s3 = (const float*)d_in[28]; const float* h3 = (const float*)d_in[29];
    const float* iW4= (const float*)d_in[30]; const float* ib4= (const float*)d_in[31];

    float* out_d      = (float*)d_out;                 // [2,128,6000]
    float* out_logits = out_d + (long)B_ * C_ * N_;    // [2,6000]

    float* f = (float*)d_ws;
    long off = 0;
    auto alloc = [&](long n) { float* p = f + off; off += n; return p; };
    float* featA = alloc(384000);
    float* featB = alloc(384000);
    float* q16f  = alloc(800000);    // Q16 [8][Nq][32] u16
    float* k16f  = alloc(800000);    // K16 [8][Nkpad][32] u16
    float* v16f  = alloc(1200000);   // V16 [8][48][Nkpad] u16
    float* xb    = alloc(1536000);
    float* x1raw = alloc(768000);
    float* x2raw = alloc(192000);
    float* x3raw = alloc(48000);
    float* plb   = alloc(100000);
    float* pacc  = alloc(3200000);   // [8][KS][Nq][32] KS-split partials
    float* zst   = alloc(512);       // stats accumulators (zeroed by prep)
    float* wreg  = alloc(250000);
    (void)ws_size; (void)in_sizes; (void)n_in; (void)out_size;

    float* ps1 = zst;        float* pq1 = zst + 128;
    float* ps2 = zst + 256;  float* pq2 = zst + 288;
    float* ps3 = zst + 320;  float* pq3 = zst + 328;

    u16* wq_h  = (u16*)wreg;
    u16* wk_h  = wq_h + 49152;
    u16* wv_h  = wk_h + 49152;
    u16* wm_h  = wv_h + 49152;
    u16* wc1_h = wm_h + 49152;
    u16* wc2_h = wc1_h + 196608;
    u16* w1_h  = wc2_h + 98304;

    u16* Q16 = (u16*)q16f;
    u16* K16 = (u16*)k16f;
    u16* V16 = (u16*)v16f;

    prep_kernel<<<dim3(768), 256, 0, stream>>>(Wq, Wk, Wv, Wm, Wc1, Wc2, iW1,
                                               wq_h, wk_h, wv_h, wm_h, wc1_h, wc2_h, w1_h, zst);

    auto layer = [&](const float* x1, const float* x2, int Nq, int Nk,
                     const float* maskl, int li, int KS, int chunkLen,
                     float* outF, float* outR) {
        const int Nkpad = KS * chunkLen;                 // >= Nk, chunkLen mult of 64
        const int npad  = maskl ? 0 : (Nkpad - Nk);      // masked layer handles pads via mask
        qkv_kernel<<<dim3((max(Nq, Nkpad) + 63) / 64, 6, B_), 256, 0, stream>>>(
            x1, x2, Nq, Nk, Nkpad,
            wq_h + (long)li * 16384, wk_h + (long)li * 16384, wv_h + (long)li * 16384,
            bq + li * 128, bk + li * 128, bv + li * 128, Q16, K16, V16);
        const int qblocks = (Nq + 127) / 128;
        if (maskl)
            attn_partial<true><<<dim3(qblocks * KS * 8), 256, 0, stream>>>(
                Q16, K16, V16, maskl, plb, pacc, Nq, Nk, Nkpad, KS, chunkLen, npad);
        else
            attn_partial<false><<<dim3(qblocks * KS * 8), 256, 0, stream>>>(
                Q16, K16, V16, nullptr, plb, pacc, Nq, Nk, Nkpad, KS, chunkLen, npad);
        epi_kernel<<<dim3((Nq + 31) / 32, B_), 256, 0, stream>>>(
            plb, pacc, KS, x1,
            wm_h + (long)li * 16384, bm + li * 128,
            wc1_h + (long)li * 65536, bc1 + li * 256, bns + li * 256, bnsh + li * 256,
            wc2_h + (long)li * 32768, bc2 + li * 128,
            outF, outR, Nq);
    };

    layer(fpX,   dX,    M_, N_, lgin,    0, 8, 768, featA, nullptr);   // Nkpad 6144
    layer(featA, featA, M_, M_, nullptr, 1, 8, 192, featB, nullptr);   // Nkpad 1536, npad 36
    layer(dX,    featB, N_, M_, nullptr, 2, 2, 768, out_d, xb);        // Nkpad 1536, npad 36

    tail1_kernel<<<dim3((N_ + 63) / 64, B_), 256, 0, stream>>>(xb, w1_h, ib1, x1raw, ps1, pq1, N_);
    tail_par<64, 16, true><<<dim3((N_ + 63) / 64, B_), 256, 0, stream>>>(
        x1raw, ps1, pq1, s1, h1, iW2, ib2, ps2, pq2, x2raw, N_);
    tail_par<16, 4, true><<<dim3((N_ + 63) / 64, B_), 256, 0, stream>>>(
        x2raw, ps2, pq2, s2, h2, iW3, ib3, ps3, pq3, x3raw, N_);
    tail_par<4, 1, false><<<dim3((N_ + 63) / 64, B_), 256, 0, stream>>>(
        x3raw, ps3, pq3, s3, h3, iW4, ib4, nullptr, nullptr, out_logits, N_);
}